// Round 1
// baseline (349.093 us; speedup 1.0000x reference)
//
#include <hip/hip_runtime.h>

// Problem constants (match reference)
#define BN 8
#define HN 256
#define WN 256
#define KN 8
#define CN 64
// R_NDC = 1.5/256*2 = 3/256 ; R_NDC^2 = 9/65536 (exactly representable)
#define R2 0.0001373291015625f

// One block handles 64 consecutive pixels along W (W=256 -> 4 blocks per row).
// Phases:
//  1) coalesced load of dist/z/idx (512 consecutive elems), alpha + cumprod -> LDS weights
//  2) gather: 16 lanes per pixel, float4 per lane (=64 channels), 4 pixels per wave
//     per instruction; zero-weight slots exec-masked (saves ~15% gather traffic)
//  3) transpose via LDS, coalesced channel-major output writes
__global__ __launch_bounds__(256) void rast_blend_kernel(
    const float* __restrict__ dist,
    const float* __restrict__ zbuf,
    const int*   __restrict__ pidx,
    const float* __restrict__ feat,
    float*       __restrict__ out)
{
    __shared__ float s_w[64][9];   // per-pixel per-slot weight (padded +1)
    __shared__ int   s_i[64][9];   // safe gather index (padded +1)
    __shared__ float s_o[64][65];  // [channel][pixel], padded -> 2-way aliasing only

    const int t   = threadIdx.x;
    const int blk = blockIdx.x;
    const int pixBase = blk << 6;        // first linear pixel of this block
    const int bh = pixBase >> 8;         // b*H + h   (W = 256)
    const int w0 = pixBase & 255;        // multiple of 64

    // ---------- Phase 1: alphas ----------
    const int base = pixBase << 3;       // *K, element offset into [B,H,W,K] arrays
    #pragma unroll
    for (int i = 0; i < 2; ++i) {
        const int e = t + (i << 8);      // 0..511, consecutive -> coalesced
        const float dd = dist[base + e];
        const float zz = zbuf[base + e];
        const int   ii = pidx[base + e];
        float d = dd / R2;
        float a = 1.0f - sqrtf(fminf(fmaxf(d, 0.001f), 1.0f));
        if (zz < 0.0f || ii < 0) a = 0.0f;   // both validity masks
        s_w[e >> 3][e & 7] = a;
        s_i[e >> 3][e & 7] = (ii >= 0) ? ii : 0;
    }
    __syncthreads();

    // ---------- Phase 1b: front-to-back cumprod (w_k = a_k * prod_{j<k}(1-a_j)) ----------
    if (t < 64) {
        float tr = 1.0f;
        #pragma unroll
        for (int k = 0; k < KN; ++k) {
            const float a = s_w[t][k];
            s_w[t][k] = a * tr;
            tr *= (1.0f - a);
        }
    }
    __syncthreads();

    // ---------- Phase 2: gather + weighted accumulate ----------
    const int wv  = t >> 6;      // wave 0..3
    const int ln  = t & 63;      // lane
    const int sub = ln >> 4;     // pixel-within-quad 0..3
    const int q   = ln & 15;     // channel quad: channels 4q..4q+3
    #pragma unroll
    for (int it = 0; it < 4; ++it) {
        const int p = (wv << 4) + (it << 2) + sub;   // pixel 0..63
        float ax = 0.0f, ay = 0.0f, az = 0.0f, aw = 0.0f;
        #pragma unroll
        for (int k = 0; k < KN; ++k) {
            const float wk = s_w[p][k];              // broadcast within 16-lane group
            if (wk > 0.0f) {                         // masked lanes fetch nothing
                const float4* fp = (const float4*)(feat + ((size_t)s_i[p][k] << 6)) + q;
                const float4 f = *fp;                // 16B aligned, 256B row per pixel
                ax = fmaf(wk, f.x, ax);
                ay = fmaf(wk, f.y, ay);
                az = fmaf(wk, f.z, az);
                aw = fmaf(wk, f.w, aw);
            }
        }
        const int c0 = q << 2;
        s_o[c0 + 0][p] = ax;     // bank = (4q+j+p)%32 -> 2-way (free)
        s_o[c0 + 1][p] = ay;
        s_o[c0 + 2][p] = az;
        s_o[c0 + 3][p] = aw;
    }
    __syncthreads();

    // ---------- Phase 3: coalesced output writes ----------
    const int b = bh >> 8;       // bh / H  (H = 256)
    const int h = bh & 255;      // bh % H
    const size_t outBase = ((size_t)b * CN) * (HN * WN) + (size_t)h * WN + w0;
    #pragma unroll
    for (int cc = 0; cc < 16; ++cc) {
        const int c = (t >> 6) + (cc << 2);
        out[outBase + (size_t)c * (HN * WN) + ln] = s_o[c][ln];  // 256B/wave contiguous
    }
}

extern "C" void kernel_launch(void* const* d_in, const int* in_sizes, int n_in,
                              void* d_out, int out_size, void* d_ws, size_t ws_size,
                              hipStream_t stream) {
    const float* dist = (const float*)d_in[0];
    const float* zbuf = (const float*)d_in[1];
    const int*   pidx = (const int*)d_in[2];
    const float* feat = (const float*)d_in[3];
    float* out = (float*)d_out;

    const int nPix = BN * HN * WN;               // 524288
    const int grid = nPix / 64;                  // 8192 blocks
    rast_blend_kernel<<<grid, 256, 0, stream>>>(dist, zbuf, pidx, feat, out);
}